// Round 1
// 276.517 us; speedup vs baseline: 1.0345x; 1.0345x over previous
//
#include <hip/hip_runtime.h>
#include <hip/hip_bf16.h>
#include <math.h>

// GATNet: hh = h@W_emb+b_emb -> GAT(8 heads,32,residual) -> GAT(1 head,32) -> out f32.
// Edge-feature branch of the reference is dead code (del e_feat) -> skipped.
// R12: dispatch-chain reduction 13->10. (a) deg folded into prep (blockIdx.y job 4);
// (b) emb-GEMM + fc1-GEMM fused into one kernel via swizzled 32KB LDS hh-tile
//     (hh still written to global for fc2 residual); fill folded into same dispatch
//     as a block-range tail (needs only scan; gemm part needs only prep);
// (c) scan_kernel serial 256-add chain replaced by shfl wave-scan.
// agg1/agg2/bn_stats/fc2 kept bit-identical to R11 (verified).

#define HDIM 256
#define NHEADS 8
#define ODIM 32

typedef unsigned short u16;
typedef __attribute__((ext_vector_type(8))) short short8;
typedef __attribute__((ext_vector_type(4))) float f32x4;

__device__ __forceinline__ float bf2f(u16 u) { return __uint_as_float(((unsigned)u) << 16); }
__device__ __forceinline__ u16 f2bf(float f) {
    unsigned x = __float_as_uint(f);
    return (u16)((x + 0x7FFFu + ((x >> 16) & 1u)) >> 16);  // RNE
}

// ---------------- prep: batched cvt + B swizzles + deg ----------------
__global__ __launch_bounds__(256) void prep_kernel(const float* __restrict__ in_h, const float* __restrict__ W_emb,
                                                   const float* __restrict__ fc1, const float* __restrict__ fc2,
                                                   const int* __restrict__ dstv, int* __restrict__ deg,
                                                   u16* __restrict__ Ah, u16* __restrict__ Bemb,
                                                   u16* __restrict__ Bfc1, u16* __restrict__ Bfc2,
                                                   int n4, int E, int N) {
    int job = blockIdx.y;
    int idx = blockIdx.x * 256 + threadIdx.x;
    if (job == 0) {
        if (idx >= n4) return;
        float4 v = ((const float4*)in_h)[idx];
        ushort4 o = {f2bf(v.x), f2bf(v.y), f2bf(v.z), f2bf(v.w)};
        ((ushort4*)Ah)[idx] = o;
        return;
    }
    if (job == 4) {  // degree count (independent of cvt jobs; deg pre-zeroed by memset)
        if (idx < E) {
            unsigned d = (unsigned)dstv[idx];
            if (d < (unsigned)N) atomicAdd(&deg[d], 1);
        }
        return;
    }
    const float* B;
    u16* O;
    int K, NC;
    if (job == 1) { B = W_emb; O = Bemb; K = 128; NC = 256; }
    else if (job == 2) { B = fc1; O = Bfc1; K = 256; NC = 256; }
    else { B = fc2; O = Bfc2; K = 256; NC = 32; }
    int KB = K / 32;
    int TOT = (NC / 16) * KB * 64;
    if (idx >= TOT) return;
    int lane = idx & 63;
    int kb = (idx >> 6) % KB;
    int ct = (idx >> 6) / KB;
    int n = ct * 16 + (lane & 15);
    int k0 = kb * 32 + (lane >> 4) * 8;
    u16* dst = O + (size_t)idx * 8;
#pragma unroll
    for (int j = 0; j < 8; j++) dst[j] = f2bf(B[(size_t)(k0 + j) * NC + n]);
}

// ---------------- CSR scan (wave-parallel) ----------------
__global__ __launch_bounds__(256) void scan_kernel(const int* __restrict__ deg, int* __restrict__ offs,
                                                   int* __restrict__ cursor, int n) {
    __shared__ int wsum[4];
    int t = threadIdx.x;
    int chunk = (n + 255) / 256;
    int lo = t * chunk, hi = lo + chunk;
    if (hi > n) hi = n;
    if (lo > n) lo = n;
    int s = 0;
    for (int i = lo; i < hi; i++) s += deg[i];
    // inclusive wave scan of s
    int v = s;
#pragma unroll
    for (int d = 1; d < 64; d <<= 1) {
        int nb = __shfl_up(v, d, 64);
        if ((t & 63) >= d) v += nb;
    }
    if ((t & 63) == 63) wsum[t >> 6] = v;
    __syncthreads();
    int woff = 0;
#pragma unroll
    for (int w = 0; w < 4; w++)
        if (w < (t >> 6)) woff += wsum[w];
    int run = woff + v - s;  // exclusive prefix for this thread's chunk
    for (int i = lo; i < hi; i++) {
        offs[i] = run;
        cursor[i] = run;
        run += deg[i];
    }
    if (t == 255) offs[n] = run;  // thread 255's chunk is clamped at n -> run == total
}

// ---------------- fused: emb GEMM -> LDS -> fc1 GEMM + elr1; tail blocks do CSR fill ----------------
__global__ __launch_bounds__(256) void fused_emb_fc1(const u16* __restrict__ Ah, const u16* __restrict__ Bemb,
                                                     const float* __restrict__ bemb, const u16* __restrict__ Bfc1,
                                                     const float* __restrict__ al, const float* __restrict__ ar,
                                                     u16* __restrict__ hh, u16* __restrict__ feat1,
                                                     u16* __restrict__ el, u16* __restrict__ er,
                                                     const int* __restrict__ src, const int* __restrict__ dstv,
                                                     int* __restrict__ cursor, int* __restrict__ srcs,
                                                     int M, int NB, int E, int N) {
    if ((int)blockIdx.x >= NB) {  // ---- CSR fill tail (whole blocks -> barriers below stay uniform) ----
        int i = ((int)blockIdx.x - NB) * 256 + (int)threadIdx.x;
        if (i < E) {
            unsigned d = (unsigned)dstv[i];
            if (d < (unsigned)N) {
                int p = atomicAdd(&cursor[d], 1);
                if ((unsigned)p < (unsigned)E) srcs[p] = src[i];
            }
        }
        return;
    }
    __shared__ u16 tile[64 * 256];  // 32 KB, reused: swizzled hh tile, then plain feat1 tile
    const int t = threadIdx.x;
    const int lane = t & 63, wq = t >> 6;
    const int rb = (int)blockIdx.x * 64;
    const int m = lane & 15, q = lane >> 4;
    const int row = rb + wq * 16 + m;

    // ---- stage 1: emb GEMM (K=128, NC=256), epilogue -> global hh + swizzled LDS ----
    short8 a0[4];
#pragma unroll
    for (int kb = 0; kb < 4; kb++) {
        if (row < M) a0[kb] = *(const short8*)(Ah + (size_t)row * 128 + kb * 32 + q * 8);
        else a0[kb] = (short8){0, 0, 0, 0, 0, 0, 0, 0};
    }
    const short8* B8 = (const short8*)Bemb;
#pragma unroll 1
    for (int ct = 0; ct < 16; ct++) {
        f32x4 acc = {0.f, 0.f, 0.f, 0.f};
#pragma unroll
        for (int kb = 0; kb < 4; kb++)
            acc = __builtin_amdgcn_mfma_f32_16x16x32_bf16(a0[kb], B8[(ct * 4 + kb) * 64 + lane], acc, 0, 0, 0);
        float bv = bemb[ct * 16 + m];
#pragma unroll
        for (int r = 0; r < 4; r++) {
            int rl = wq * 16 + q * 4 + r;
            int ro = rb + rl;
            u16 hv = 0;
            if (ro < M) {
                hv = f2bf(acc[r] + bv);
                hh[(size_t)ro * 256 + ct * 16 + m] = hv;
            }
            int byte = rl * 512 + (ct * 16 + m) * 2;
            tile[(byte ^ ((rl & 7) << 4)) >> 1] = hv;  // XOR-swizzle: b128 reads below are 2-way (free)
        }
    }
    __syncthreads();

    // ---- stage 2: fc1 A-fragments straight from LDS (no global hh re-read) ----
    short8 af[8];
    {
        int rl = wq * 16 + m;
#pragma unroll
        for (int kb = 0; kb < 8; kb++) {
            int byte = rl * 512 + kb * 64 + q * 16;
            af[kb] = *(const short8*)(tile + ((byte ^ ((rl & 7) << 4)) >> 1));
        }
    }
    __syncthreads();  // all af reads drained before tile is overwritten as feat1 tile

    const short8* Bf = (const short8*)Bfc1;
#pragma unroll 1
    for (int ct = 0; ct < 16; ct++) {
        f32x4 acc = {0.f, 0.f, 0.f, 0.f};
#pragma unroll
        for (int kb = 0; kb < 8; kb++)
            acc = __builtin_amdgcn_mfma_f32_16x16x32_bf16(af[kb], Bf[(ct * 8 + kb) * 64 + lane], acc, 0, 0, 0);
#pragma unroll
        for (int r = 0; r < 4; r++) {
            int rl = wq * 16 + q * 4 + r;
            int ro = rb + rl;
            u16 v = 0;
            if (ro < M) {
                v = f2bf(acc[r]);
                feat1[(size_t)ro * 256 + ct * 16 + m] = v;
            }
            tile[rl * 256 + ct * 16 + m] = v;  // plain layout for elr epilogue
        }
    }
    __syncthreads();

    // ---- stage 3: el/er epilogue from feat1 tile ----
#pragma unroll
    for (int task = t; task < 512; task += 256) {
        int nl = task >> 3, h2 = task & 7;
        int node = rb + nl;
        if (node >= M) continue;
        float a_ = 0.f, b_ = 0.f;
#pragma unroll
        for (int d = 0; d < 32; d++) {
            float fv = bf2f(tile[nl * 256 + h2 * 32 + d]);
            a_ += fv * al[h2 * 32 + d];
            b_ += fv * ar[h2 * 32 + d];
        }
        el[node * 8 + h2] = f2bf(a_);
        er[node * 8 + h2] = f2bf(b_);
    }
}

// exp(leaky_relu(l)); logits O(0.1), max-subtraction unnecessary (identical ratios)
__device__ __forceinline__ float edgew(float l) {
    l = (l > 0.f) ? l : 0.2f * l;
    l = fminf(fmaxf(l, -30.f), 30.f);
    return __expf(l);
}

// ---------------- agg1: fused edge weights (NO stats fusion) ----------------
__global__ __launch_bounds__(256) void agg1_fused(const u16* __restrict__ feat, const u16* __restrict__ el,
                                                  const u16* __restrict__ er, const int* __restrict__ offs,
                                                  const int* __restrict__ srcs, u16* __restrict__ rst, int N, int E) {
    const int node = blockIdx.x * 4 + (threadIdx.x >> 6);
    const int lane = threadIdx.x & 63;
    if (node >= N) return;
    const int h = lane >> 3;
    int beg = offs[node], end = offs[node + 1];
    if (beg < 0) beg = 0;
    if (end > E) end = E;
    float ern = bf2f(er[node * 8 + h]);
    float ax = 0.f, ay = 0.f, az = 0.f, aw = 0.f, sw = 0.f;
    int j = beg;
    int end4 = beg + ((end - beg) & ~3);
    for (; j < end4; j += 4) {  // 4-deep software pipeline
        int s0 = srcs[j], s1 = srcs[j + 1], s2 = srcs[j + 2], s3 = srcs[j + 3];
        unsigned c0 = (unsigned)s0 < (unsigned)N, c1 = (unsigned)s1 < (unsigned)N;
        unsigned c2 = (unsigned)s2 < (unsigned)N, c3 = (unsigned)s3 < (unsigned)N;
        s0 = c0 ? s0 : 0; s1 = c1 ? s1 : 0; s2 = c2 ? s2 : 0; s3 = c3 ? s3 : 0;
        u16 e0 = el[s0 * 8 + h], e1 = el[s1 * 8 + h], e2 = el[s2 * 8 + h], e3 = el[s3 * 8 + h];
        ushort4 f0 = *(const ushort4*)(feat + (size_t)s0 * 256 + lane * 4);
        ushort4 f1 = *(const ushort4*)(feat + (size_t)s1 * 256 + lane * 4);
        ushort4 f2 = *(const ushort4*)(feat + (size_t)s2 * 256 + lane * 4);
        ushort4 f3 = *(const ushort4*)(feat + (size_t)s3 * 256 + lane * 4);
        float w0 = c0 ? edgew(bf2f(e0) + ern) : 0.f;
        float w1 = c1 ? edgew(bf2f(e1) + ern) : 0.f;
        float w2 = c2 ? edgew(bf2f(e2) + ern) : 0.f;
        float w3 = c3 ? edgew(bf2f(e3) + ern) : 0.f;
        sw += w0 + w1 + w2 + w3;
        ax += w0 * bf2f(f0.x) + w1 * bf2f(f1.x) + w2 * bf2f(f2.x) + w3 * bf2f(f3.x);
        ay += w0 * bf2f(f0.y) + w1 * bf2f(f1.y) + w2 * bf2f(f2.y) + w3 * bf2f(f3.y);
        az += w0 * bf2f(f0.z) + w1 * bf2f(f1.z) + w2 * bf2f(f2.z) + w3 * bf2f(f3.z);
        aw += w0 * bf2f(f0.w) + w1 * bf2f(f1.w) + w2 * bf2f(f2.w) + w3 * bf2f(f3.w);
    }
    for (; j < end; j++) {
        int s = srcs[j];
        if ((unsigned)s >= (unsigned)N) continue;
        float wv = edgew(bf2f(el[s * 8 + h]) + ern);
        ushort4 f4 = *(const ushort4*)(feat + (size_t)s * 256 + lane * 4);
        sw += wv;
        ax += wv * bf2f(f4.x);
        ay += wv * bf2f(f4.y);
        az += wv * bf2f(f4.z);
        aw += wv * bf2f(f4.w);
    }
    float inv = 1.f / (sw + 1e-16f);
    ushort4 o;
    o.x = f2bf(ax * inv); o.y = f2bf(ay * inv); o.z = f2bf(az * inv); o.w = f2bf(aw * inv);
    *(ushort4*)(rst + (size_t)node * 256 + lane * 4) = o;
}

// ---------------- bn stats, separate low-contention kernels ----------------
__global__ __launch_bounds__(256) void bn_stats256(const u16* __restrict__ X, float* __restrict__ stats,
                                                   int rows, int RPB) {
    int t = threadIdx.x;
    int rbeg = blockIdx.x * RPB;
    int rend = rbeg + RPB;
    if (rend > rows) rend = rows;
    float s = 0.f, s2 = 0.f;
    for (int r = rbeg; r < rend; r++) {
        float x = bf2f(X[(long)r * 256 + t]);
        s += x;
        s2 += x * x;
    }
    atomicAdd(&stats[t], s);
    atomicAdd(&stats[256 + t], s2);
}

__global__ __launch_bounds__(256) void bn_stats32(const float* __restrict__ X, float* __restrict__ stats,
                                                  int rows, int RPB) {
    __shared__ float ss[256], ss2[256];
    int t = threadIdx.x, c = t & 31, rs = t >> 5;
    int rbeg = blockIdx.x * RPB;
    int rend = rbeg + RPB;
    if (rend > rows) rend = rows;
    float s = 0.f, s2 = 0.f;
    for (int r = rbeg + rs; r < rend; r += 8) {
        float x = X[(long)r * 32 + c];
        s += x;
        s2 += x * x;
    }
    ss[t] = s;
    ss2[t] = s2;
    __syncthreads();
    if (t < 32) {
        for (int j = 32; j < 256; j += 32) { s += ss[t + j]; s2 += ss2[t + j]; }
        atomicAdd(&stats[c], s);
        atomicAdd(&stats[32 + c], s2);
    }
}

// ---------------- fc2 GEMM with fused bn_apply1(+residual) on A, + fused elr2 ----------------
__global__ __launch_bounds__(256) void gemm_fc2_fused(const u16* __restrict__ rst, const u16* __restrict__ hh,
                                                      const float* __restrict__ stats, const float* __restrict__ g,
                                                      const float* __restrict__ b, const u16* __restrict__ Bsw,
                                                      const float* __restrict__ al2, const float* __restrict__ ar2,
                                                      float* __restrict__ feat2, float* __restrict__ el2,
                                                      float* __restrict__ er2, int M, float invN) {
    __shared__ float sc[256], sh[256];
    __shared__ float tile[64][32];
    const int t = threadIdx.x;
    {
        float mu = stats[t] * invN;
        float var = fmaxf(stats[256 + t] * invN - mu * mu, 0.f);
        float s = g[t] * rsqrtf(var + 1e-5f);
        sc[t] = s;
        sh[t] = b[t] - mu * s;
    }
    __syncthreads();
    const int lane = t & 63, wq = t >> 6;
    const int rb = blockIdx.x * 64;
    const int m = lane & 15, q = lane >> 4;
    const int row = rb + wq * 16 + m;
    short8 a[8];
#pragma unroll
    for (int kb = 0; kb < 8; kb++) {
        if (row < M) {
            int k0 = kb * 32 + q * 8;
            ushort4 r01 = *(const ushort4*)(rst + (size_t)row * 256 + k0);
            ushort4 r23 = *(const ushort4*)(rst + (size_t)row * 256 + k0 + 4);
            ushort4 h01 = *(const ushort4*)(hh + (size_t)row * 256 + k0);
            ushort4 h23 = *(const ushort4*)(hh + (size_t)row * 256 + k0 + 4);
            u16 rv[8] = {r01.x, r01.y, r01.z, r01.w, r23.x, r23.y, r23.z, r23.w};
            u16 hv[8] = {h01.x, h01.y, h01.z, h01.w, h23.x, h23.y, h23.z, h23.w};
            short8 av;
#pragma unroll
            for (int j = 0; j < 8; j++) {
                int c = k0 + j;
                float y = sc[c] * bf2f(rv[j]) + sh[c];
                y = (y > 0.f) ? y : expm1f(y);
                av[j] = (short)f2bf(bf2f(hv[j]) + y);
            }
            a[kb] = av;
        } else a[kb] = (short8){0, 0, 0, 0, 0, 0, 0, 0};
    }
    const short8* B8 = (const short8*)Bsw;
#pragma unroll
    for (int ct = 0; ct < 2; ct++) {
        f32x4 acc = {0.f, 0.f, 0.f, 0.f};
#pragma unroll
        for (int kb = 0; kb < 8; kb++)
            acc = __builtin_amdgcn_mfma_f32_16x16x32_bf16(a[kb], B8[(ct * 8 + kb) * 64 + lane], acc, 0, 0, 0);
#pragma unroll
        for (int r = 0; r < 4; r++) {
            int rl = wq * 16 + q * 4 + r;
            int ro = rb + rl;
            float v = 0.f;
            if (ro < M) {
                v = acc[r];
                feat2[(size_t)ro * 32 + ct * 16 + m] = v;
            }
            tile[rl][ct * 16 + m] = v;
        }
    }
    __syncthreads();
    if (t < 64) {
        int node = rb + t;
        if (node < M) {
            float a_ = 0.f, b_ = 0.f;
#pragma unroll
            for (int d = 0; d < 32; d++) {
                float fv = tile[t][d];
                a_ += fv * al2[d];
                b_ += fv * ar2[d];
            }
            el2[node] = a_;
            er2[node] = b_;
        }
    }
}

// ---------------- agg2: fused edge weights (NO stats fusion) ----------------
__global__ __launch_bounds__(256) void agg2_fused(const float* __restrict__ feat, const float* __restrict__ el,
                                                  const float* __restrict__ er, const int* __restrict__ offs,
                                                  const int* __restrict__ srcs, float* __restrict__ rst,
                                                  int N, int E) {
    const int t = threadIdx.x;
    const int node = blockIdx.x * 8 + (t >> 5);
    const int d = t & 31;
    if (node >= N) return;
    int beg = offs[node], end = offs[node + 1];
    if (beg < 0) beg = 0;
    if (end > E) end = E;
    float ern = er[node];
    float acc = 0.f, sw = 0.f;
#pragma unroll 2
    for (int j = beg; j < end; j++) {
        int s = srcs[j];
        if ((unsigned)s >= (unsigned)N) continue;
        float wv = edgew(el[s] + ern);
        sw += wv;
        acc += wv * feat[(size_t)s * 32 + d];
    }
    rst[(size_t)node * 32 + d] = acc / (sw + 1e-16f);
}

// ---------------- final bn + elu -> f32 out ----------------
__global__ __launch_bounds__(256) void bn_apply2(const float* __restrict__ rst, const float* __restrict__ stats,
                                                 const float* __restrict__ g, const float* __restrict__ b,
                                                 float* __restrict__ out, int total, float invN) {
    int idx = blockIdx.x * 256 + threadIdx.x;
    if (idx >= total) return;
    int c = idx & 31;
    float mu = stats[c] * invN;
    float var = fmaxf(stats[32 + c] * invN - mu * mu, 0.f);
    float y = g[c] * (rst[idx] - mu) * rsqrtf(var + 1e-5f) + b[c];
    y = (y > 0.f) ? y : expm1f(y);
    out[idx] = y;
}

extern "C" void kernel_launch(void* const* d_in, const int* in_sizes, int n_in, void* d_out, int out_size, void* d_ws,
                              size_t ws_size, hipStream_t stream) {
    const int N = out_size / ODIM;
    const int E = in_sizes[2];

    const int* src = (const int*)d_in[2];
    const int* dst = (const int*)d_in[3];
    const float* in_h = (const float*)d_in[0];
    const float* W_emb = (const float*)d_in[4];  const float* b_emb = (const float*)d_in[5];
    const float* fc1 = (const float*)d_in[18];   const float* al1 = (const float*)d_in[19];
    const float* ar1 = (const float*)d_in[20];
    const float* g1 = (const float*)d_in[21];    const float* b1 = (const float*)d_in[22];
    const float* fc2 = (const float*)d_in[23];   const float* al2 = (const float*)d_in[24];
    const float* ar2 = (const float*)d_in[25];
    const float* g2 = (const float*)d_in[26];    const float* b2 = (const float*)d_in[27];
    float* out = (float*)d_out;

    // ---- ws layout (~26 MB) ----
    char* base = (char*)d_ws;
    size_t off = 0;
    auto alloc = [&](size_t bytes) { void* p = base + off; off += (bytes + 63) & ~63ull; return p; };
    char* zb   = (char*)alloc((size_t)N * 4 + 512 * 4 + 64 * 4);
    int* deg   = (int*)zb;
    float* stats  = (float*)(zb + (size_t)N * 4);
    float* stats2 = stats + 512;
    int* offs  = (int*)alloc((size_t)(N + 1) * 4);
    int* cursor = (int*)alloc((size_t)N * 4);
    int* srcs  = (int*)alloc((size_t)E * 4);
    u16* Ah    = (u16*)alloc((size_t)N * 128 * 2);
    u16* Bemb  = (u16*)alloc((size_t)128 * 256 * 2);
    u16* Bfc1  = (u16*)alloc((size_t)256 * 256 * 2);
    u16* Bfc2  = (u16*)alloc((size_t)256 * 32 * 2);
    u16* hh    = (u16*)alloc((size_t)N * HDIM * 2);
    u16* feat1 = (u16*)alloc((size_t)N * HDIM * 2);
    u16* el1   = (u16*)alloc((size_t)N * 8 * 2);
    u16* er1   = (u16*)alloc((size_t)N * 8 * 2);
    u16* rst   = (u16*)alloc((size_t)N * HDIM * 2);
    float* feat2 = (float*)alloc((size_t)N * 32 * 4);
    float* el2 = (float*)alloc((size_t)N * 4);
    float* er2 = (float*)alloc((size_t)N * 4);
    float* rst2 = (float*)alloc((size_t)N * 32 * 4);

    const int NB64 = (N + 63) / 64;
    const int NBF = (E + 255) / 256;  // fill tail blocks

    hipMemsetAsync(zb, 0, (size_t)N * 4 + 512 * 4 + 64 * 4, stream);
    prep_kernel<<<dim3((N * 128 / 4 + 255) / 256, 5), 256, 0, stream>>>(in_h, W_emb, fc1, fc2, dst, deg,
                                                                        Ah, Bemb, Bfc1, Bfc2, N * 128 / 4, E, N);
    scan_kernel<<<1, 256, 0, stream>>>(deg, offs, cursor, N);
    fused_emb_fc1<<<NB64 + NBF, 256, 0, stream>>>(Ah, Bemb, b_emb, Bfc1, al1, ar1, hh, feat1, el1, er1,
                                                  src, dst, cursor, srcs, N, NB64, E, N);
    agg1_fused<<<(N + 3) / 4, 256, 0, stream>>>(feat1, el1, er1, offs, srcs, rst, N, E);
    bn_stats256<<<(N + 39) / 40, 256, 0, stream>>>(rst, stats, N, 40);
    gemm_fc2_fused<<<NB64, 256, 0, stream>>>(rst, hh, stats, g1, b1, Bfc2, al2, ar2, feat2, el2, er2, N, 1.f / N);
    agg2_fused<<<(N + 7) / 8, 256, 0, stream>>>(feat2, el2, er2, offs, srcs, rst2, N, E);
    bn_stats32<<<(N + 63) / 64, 256, 0, stream>>>(rst2, stats2, N, 64);
    bn_apply2<<<(N * ODIM + 255) / 256, 256, 0, stream>>>(rst2, stats2, g2, b2, out, N * ODIM, 1.f / N);
}

// Round 2
// 259.449 us; speedup vs baseline: 1.1026x; 1.0658x over previous
//
#include <hip/hip_runtime.h>
#include <hip/hip_bf16.h>
#include <math.h>

// GATNet: hh = h@W_emb+b_emb -> GAT(8 heads,32,residual) -> GAT(1 head,32) -> out f32.
// Edge-feature branch of the reference is dead code (del e_feat) -> skipped.
// R13: attack fused_emb_fc1's latency-bound 43us (MfmaUtil 1.5%, Occ 9%).
// (a) GEMM restructured 64-row -> 16-row tiles: 157 -> 625 blocks (~2.4 blocks/CU so
//     2-3 waves/SIMD hide the L3-hit B-load latency); waves split the 16 column-tiles
//     (4 ct each) instead of rows; hh handoff via 8KB swizzled LDS tile.
// (b) CSR fill split back to its own dispatch for unambiguous profile attribution
//     (R12 fused it; can't tell GEMM latency from fill-atomic latency in one number).
// agg1/agg2/bn_stats/fc2/prep/scan kept bit-identical to R12 (verified).

#define HDIM 256
#define NHEADS 8
#define ODIM 32

typedef unsigned short u16;
typedef __attribute__((ext_vector_type(8))) short short8;
typedef __attribute__((ext_vector_type(4))) float f32x4;

__device__ __forceinline__ float bf2f(u16 u) { return __uint_as_float(((unsigned)u) << 16); }
__device__ __forceinline__ u16 f2bf(float f) {
    unsigned x = __float_as_uint(f);
    return (u16)((x + 0x7FFFu + ((x >> 16) & 1u)) >> 16);  // RNE
}

// ---------------- prep: batched cvt + B swizzles + deg ----------------
__global__ __launch_bounds__(256) void prep_kernel(const float* __restrict__ in_h, const float* __restrict__ W_emb,
                                                   const float* __restrict__ fc1, const float* __restrict__ fc2,
                                                   const int* __restrict__ dstv, int* __restrict__ deg,
                                                   u16* __restrict__ Ah, u16* __restrict__ Bemb,
                                                   u16* __restrict__ Bfc1, u16* __restrict__ Bfc2,
                                                   int n4, int E, int N) {
    int job = blockIdx.y;
    int idx = blockIdx.x * 256 + threadIdx.x;
    if (job == 0) {
        if (idx >= n4) return;
        float4 v = ((const float4*)in_h)[idx];
        ushort4 o = {f2bf(v.x), f2bf(v.y), f2bf(v.z), f2bf(v.w)};
        ((ushort4*)Ah)[idx] = o;
        return;
    }
    if (job == 4) {  // degree count (independent of cvt jobs; deg pre-zeroed by memset)
        if (idx < E) {
            unsigned d = (unsigned)dstv[idx];
            if (d < (unsigned)N) atomicAdd(&deg[d], 1);
        }
        return;
    }
    const float* B;
    u16* O;
    int K, NC;
    if (job == 1) { B = W_emb; O = Bemb; K = 128; NC = 256; }
    else if (job == 2) { B = fc1; O = Bfc1; K = 256; NC = 256; }
    else { B = fc2; O = Bfc2; K = 256; NC = 32; }
    int KB = K / 32;
    int TOT = (NC / 16) * KB * 64;
    if (idx >= TOT) return;
    int lane = idx & 63;
    int kb = (idx >> 6) % KB;
    int ct = (idx >> 6) / KB;
    int n = ct * 16 + (lane & 15);
    int k0 = kb * 32 + (lane >> 4) * 8;
    u16* dst = O + (size_t)idx * 8;
#pragma unroll
    for (int j = 0; j < 8; j++) dst[j] = f2bf(B[(size_t)(k0 + j) * NC + n]);
}

// ---------------- CSR scan (wave-parallel) ----------------
__global__ __launch_bounds__(256) void scan_kernel(const int* __restrict__ deg, int* __restrict__ offs,
                                                   int* __restrict__ cursor, int n) {
    __shared__ int wsum[4];
    int t = threadIdx.x;
    int chunk = (n + 255) / 256;
    int lo = t * chunk, hi = lo + chunk;
    if (hi > n) hi = n;
    if (lo > n) lo = n;
    int s = 0;
    for (int i = lo; i < hi; i++) s += deg[i];
    // inclusive wave scan of s
    int v = s;
#pragma unroll
    for (int d = 1; d < 64; d <<= 1) {
        int nb = __shfl_up(v, d, 64);
        if ((t & 63) >= d) v += nb;
    }
    if ((t & 63) == 63) wsum[t >> 6] = v;
    __syncthreads();
    int woff = 0;
#pragma unroll
    for (int w = 0; w < 4; w++)
        if (w < (t >> 6)) woff += wsum[w];
    int run = woff + v - s;  // exclusive prefix for this thread's chunk
    for (int i = lo; i < hi; i++) {
        offs[i] = run;
        cursor[i] = run;
        run += deg[i];
    }
    if (t == 255) offs[n] = run;  // thread 255's chunk is clamped at n -> run == total
}

// ---------------- CSR fill (separate dispatch for attribution) ----------------
__global__ __launch_bounds__(256) void fill_kernel(const int* __restrict__ src, const int* __restrict__ dstv,
                                                   int* __restrict__ cursor, int* __restrict__ srcs, int E, int N) {
    int i = blockIdx.x * 256 + threadIdx.x;
    if (i < E) {
        unsigned d = (unsigned)dstv[i];
        if (d < (unsigned)N) {
            int p = atomicAdd(&cursor[d], 1);
            if ((unsigned)p < (unsigned)E) srcs[p] = src[i];
        }
    }
}

// ---------------- fused: emb GEMM -> 8KB LDS -> fc1 GEMM + elr1 (16-row tiles) ----------------
// Block = 16 output rows, 4 waves each own 4 of the 16 column-tiles (ct).
// Stage 1 (emb, K=128): every wave loads the same 16-row A fragments (4KB, L1-hit),
// computes its 4 ct, writes hh global + swizzled LDS tile.
// Stage 2 (fc1, K=256): A fragments read back from LDS (swizzled, 2-way = free),
// each wave computes its 4 ct of feat1, then el/er epilogue from plain LDS tile.
__global__ __launch_bounds__(256) void fused_emb_fc1(const u16* __restrict__ Ah, const u16* __restrict__ Bemb,
                                                     const float* __restrict__ bemb, const u16* __restrict__ Bfc1,
                                                     const float* __restrict__ al, const float* __restrict__ ar,
                                                     u16* __restrict__ hh, u16* __restrict__ feat1,
                                                     u16* __restrict__ el, u16* __restrict__ er, int M) {
    __shared__ u16 tile[16 * 256];  // 8 KB, reused: swizzled hh tile, then plain feat1 tile
    const int t = threadIdx.x;
    const int lane = t & 63, w = t >> 6;
    const int rb = (int)blockIdx.x * 16;
    const int m = lane & 15, q = lane >> 4;
    const int arow = rb + m;

    // ---- stage 1: emb GEMM (K=128), this wave's ct = w*4 .. w*4+3 ----
    short8 a0[4];
#pragma unroll
    for (int kb = 0; kb < 4; kb++) {
        if (arow < M) a0[kb] = *(const short8*)(Ah + (size_t)arow * 128 + kb * 32 + q * 8);
        else a0[kb] = (short8){0, 0, 0, 0, 0, 0, 0, 0};
    }
    const short8* B8 = (const short8*)Bemb;
#pragma unroll
    for (int ct2 = 0; ct2 < 4; ct2++) {
        const int ct = w * 4 + ct2;
        f32x4 acc = {0.f, 0.f, 0.f, 0.f};
#pragma unroll
        for (int kb = 0; kb < 4; kb++)
            acc = __builtin_amdgcn_mfma_f32_16x16x32_bf16(a0[kb], B8[(ct * 4 + kb) * 64 + lane], acc, 0, 0, 0);
        float bv = bemb[ct * 16 + m];
#pragma unroll
        for (int r = 0; r < 4; r++) {
            int rl = q * 4 + r;
            int ro = rb + rl;
            u16 hv = 0;
            if (ro < M) {
                hv = f2bf(acc[r] + bv);
                hh[(size_t)ro * 256 + ct * 16 + m] = hv;
            }
            int byte = rl * 512 + (ct * 16 + m) * 2;
            tile[(byte ^ ((rl & 7) << 4)) >> 1] = hv;  // XOR-swizzle: b128 reads below are ~2-way (free)
        }
    }
    __syncthreads();

    // ---- stage 2: fc1 A-fragments straight from LDS (no global hh re-read) ----
    short8 af[8];
    {
        int rl = m;
#pragma unroll
        for (int kb = 0; kb < 8; kb++) {
            int byte = rl * 512 + kb * 64 + q * 16;
            af[kb] = *(const short8*)(tile + ((byte ^ ((rl & 7) << 4)) >> 1));
        }
    }
    __syncthreads();  // all af reads drained before tile is overwritten as feat1 tile

    const short8* Bf = (const short8*)Bfc1;
#pragma unroll
    for (int ct2 = 0; ct2 < 4; ct2++) {
        const int ct = w * 4 + ct2;
        f32x4 acc = {0.f, 0.f, 0.f, 0.f};
#pragma unroll
        for (int kb = 0; kb < 8; kb++)
            acc = __builtin_amdgcn_mfma_f32_16x16x32_bf16(af[kb], Bf[(ct * 8 + kb) * 64 + lane], acc, 0, 0, 0);
#pragma unroll
        for (int r = 0; r < 4; r++) {
            int rl = q * 4 + r;
            int ro = rb + rl;
            u16 v = 0;
            if (ro < M) {
                v = f2bf(acc[r]);
                feat1[(size_t)ro * 256 + ct * 16 + m] = v;
            }
            tile[rl * 256 + ct * 16 + m] = v;  // plain layout for elr epilogue
        }
    }
    __syncthreads();

    // ---- stage 3: el/er epilogue from feat1 tile (16 nodes x 8 heads = 128 tasks) ----
    if (t < 128) {
        int nl = t >> 3, h2 = t & 7;
        int node = rb + nl;
        if (node < M) {
            float a_ = 0.f, b_ = 0.f;
#pragma unroll
            for (int d = 0; d < 32; d++) {
                float fv = bf2f(tile[nl * 256 + h2 * 32 + d]);
                a_ += fv * al[h2 * 32 + d];
                b_ += fv * ar[h2 * 32 + d];
            }
            el[node * 8 + h2] = f2bf(a_);
            er[node * 8 + h2] = f2bf(b_);
        }
    }
}

// exp(leaky_relu(l)); logits O(0.1), max-subtraction unnecessary (identical ratios)
__device__ __forceinline__ float edgew(float l) {
    l = (l > 0.f) ? l : 0.2f * l;
    l = fminf(fmaxf(l, -30.f), 30.f);
    return __expf(l);
}

// ---------------- agg1: fused edge weights (NO stats fusion) ----------------
__global__ __launch_bounds__(256) void agg1_fused(const u16* __restrict__ feat, const u16* __restrict__ el,
                                                  const u16* __restrict__ er, const int* __restrict__ offs,
                                                  const int* __restrict__ srcs, u16* __restrict__ rst, int N, int E) {
    const int node = blockIdx.x * 4 + (threadIdx.x >> 6);
    const int lane = threadIdx.x & 63;
    if (node >= N) return;
    const int h = lane >> 3;
    int beg = offs[node], end = offs[node + 1];
    if (beg < 0) beg = 0;
    if (end > E) end = E;
    float ern = bf2f(er[node * 8 + h]);
    float ax = 0.f, ay = 0.f, az = 0.f, aw = 0.f, sw = 0.f;
    int j = beg;
    int end4 = beg + ((end - beg) & ~3);
    for (; j < end4; j += 4) {  // 4-deep software pipeline
        int s0 = srcs[j], s1 = srcs[j + 1], s2 = srcs[j + 2], s3 = srcs[j + 3];
        unsigned c0 = (unsigned)s0 < (unsigned)N, c1 = (unsigned)s1 < (unsigned)N;
        unsigned c2 = (unsigned)s2 < (unsigned)N, c3 = (unsigned)s3 < (unsigned)N;
        s0 = c0 ? s0 : 0; s1 = c1 ? s1 : 0; s2 = c2 ? s2 : 0; s3 = c3 ? s3 : 0;
        u16 e0 = el[s0 * 8 + h], e1 = el[s1 * 8 + h], e2 = el[s2 * 8 + h], e3 = el[s3 * 8 + h];
        ushort4 f0 = *(const ushort4*)(feat + (size_t)s0 * 256 + lane * 4);
        ushort4 f1 = *(const ushort4*)(feat + (size_t)s1 * 256 + lane * 4);
        ushort4 f2 = *(const ushort4*)(feat + (size_t)s2 * 256 + lane * 4);
        ushort4 f3 = *(const ushort4*)(feat + (size_t)s3 * 256 + lane * 4);
        float w0 = c0 ? edgew(bf2f(e0) + ern) : 0.f;
        float w1 = c1 ? edgew(bf2f(e1) + ern) : 0.f;
        float w2 = c2 ? edgew(bf2f(e2) + ern) : 0.f;
        float w3 = c3 ? edgew(bf2f(e3) + ern) : 0.f;
        sw += w0 + w1 + w2 + w3;
        ax += w0 * bf2f(f0.x) + w1 * bf2f(f1.x) + w2 * bf2f(f2.x) + w3 * bf2f(f3.x);
        ay += w0 * bf2f(f0.y) + w1 * bf2f(f1.y) + w2 * bf2f(f2.y) + w3 * bf2f(f3.y);
        az += w0 * bf2f(f0.z) + w1 * bf2f(f1.z) + w2 * bf2f(f2.z) + w3 * bf2f(f3.z);
        aw += w0 * bf2f(f0.w) + w1 * bf2f(f1.w) + w2 * bf2f(f2.w) + w3 * bf2f(f3.w);
    }
    for (; j < end; j++) {
        int s = srcs[j];
        if ((unsigned)s >= (unsigned)N) continue;
        float wv = edgew(bf2f(el[s * 8 + h]) + ern);
        ushort4 f4 = *(const ushort4*)(feat + (size_t)s * 256 + lane * 4);
        sw += wv;
        ax += wv * bf2f(f4.x);
        ay += wv * bf2f(f4.y);
        az += wv * bf2f(f4.z);
        aw += wv * bf2f(f4.w);
    }
    float inv = 1.f / (sw + 1e-16f);
    ushort4 o;
    o.x = f2bf(ax * inv); o.y = f2bf(ay * inv); o.z = f2bf(az * inv); o.w = f2bf(aw * inv);
    *(ushort4*)(rst + (size_t)node * 256 + lane * 4) = o;
}

// ---------------- bn stats, separate low-contention kernels ----------------
__global__ __launch_bounds__(256) void bn_stats256(const u16* __restrict__ X, float* __restrict__ stats,
                                                   int rows, int RPB) {
    int t = threadIdx.x;
    int rbeg = blockIdx.x * RPB;
    int rend = rbeg + RPB;
    if (rend > rows) rend = rows;
    float s = 0.f, s2 = 0.f;
    for (int r = rbeg; r < rend; r++) {
        float x = bf2f(X[(long)r * 256 + t]);
        s += x;
        s2 += x * x;
    }
    atomicAdd(&stats[t], s);
    atomicAdd(&stats[256 + t], s2);
}

__global__ __launch_bounds__(256) void bn_stats32(const float* __restrict__ X, float* __restrict__ stats,
                                                  int rows, int RPB) {
    __shared__ float ss[256], ss2[256];
    int t = threadIdx.x, c = t & 31, rs = t >> 5;
    int rbeg = blockIdx.x * RPB;
    int rend = rbeg + RPB;
    if (rend > rows) rend = rows;
    float s = 0.f, s2 = 0.f;
    for (int r = rbeg + rs; r < rend; r += 8) {
        float x = X[(long)r * 32 + c];
        s += x;
        s2 += x * x;
    }
    ss[t] = s;
    ss2[t] = s2;
    __syncthreads();
    if (t < 32) {
        for (int j = 32; j < 256; j += 32) { s += ss[t + j]; s2 += ss2[t + j]; }
        atomicAdd(&stats[c], s);
        atomicAdd(&stats[32 + c], s2);
    }
}

// ---------------- fc2 GEMM with fused bn_apply1(+residual) on A, + fused elr2 ----------------
__global__ __launch_bounds__(256) void gemm_fc2_fused(const u16* __restrict__ rst, const u16* __restrict__ hh,
                                                      const float* __restrict__ stats, const float* __restrict__ g,
                                                      const float* __restrict__ b, const u16* __restrict__ Bsw,
                                                      const float* __restrict__ al2, const float* __restrict__ ar2,
                                                      float* __restrict__ feat2, float* __restrict__ el2,
                                                      float* __restrict__ er2, int M, float invN) {
    __shared__ float sc[256], sh[256];
    __shared__ float tile[64][32];
    const int t = threadIdx.x;
    {
        float mu = stats[t] * invN;
        float var = fmaxf(stats[256 + t] * invN - mu * mu, 0.f);
        float s = g[t] * rsqrtf(var + 1e-5f);
        sc[t] = s;
        sh[t] = b[t] - mu * s;
    }
    __syncthreads();
    const int lane = t & 63, wq = t >> 6;
    const int rb = blockIdx.x * 64;
    const int m = lane & 15, q = lane >> 4;
    const int row = rb + wq * 16 + m;
    short8 a[8];
#pragma unroll
    for (int kb = 0; kb < 8; kb++) {
        if (row < M) {
            int k0 = kb * 32 + q * 8;
            ushort4 r01 = *(const ushort4*)(rst + (size_t)row * 256 + k0);
            ushort4 r23 = *(const ushort4*)(rst + (size_t)row * 256 + k0 + 4);
            ushort4 h01 = *(const ushort4*)(hh + (size_t)row * 256 + k0);
            ushort4 h23 = *(const ushort4*)(hh + (size_t)row * 256 + k0 + 4);
            u16 rv[8] = {r01.x, r01.y, r01.z, r01.w, r23.x, r23.y, r23.z, r23.w};
            u16 hv[8] = {h01.x, h01.y, h01.z, h01.w, h23.x, h23.y, h23.z, h23.w};
            short8 av;
#pragma unroll
            for (int j = 0; j < 8; j++) {
                int c = k0 + j;
                float y = sc[c] * bf2f(rv[j]) + sh[c];
                y = (y > 0.f) ? y : expm1f(y);
                av[j] = (short)f2bf(bf2f(hv[j]) + y);
            }
            a[kb] = av;
        } else a[kb] = (short8){0, 0, 0, 0, 0, 0, 0, 0};
    }
    const short8* B8 = (const short8*)Bsw;
#pragma unroll
    for (int ct = 0; ct < 2; ct++) {
        f32x4 acc = {0.f, 0.f, 0.f, 0.f};
#pragma unroll
        for (int kb = 0; kb < 8; kb++)
            acc = __builtin_amdgcn_mfma_f32_16x16x32_bf16(a[kb], B8[(ct * 8 + kb) * 64 + lane], acc, 0, 0, 0);
#pragma unroll
        for (int r = 0; r < 4; r++) {
            int rl = wq * 16 + q * 4 + r;
            int ro = rb + rl;
            float v = 0.f;
            if (ro < M) {
                v = acc[r];
                feat2[(size_t)ro * 32 + ct * 16 + m] = v;
            }
            tile[rl][ct * 16 + m] = v;
        }
    }
    __syncthreads();
    if (t < 64) {
        int node = rb + t;
        if (node < M) {
            float a_ = 0.f, b_ = 0.f;
#pragma unroll
            for (int d = 0; d < 32; d++) {
                float fv = tile[t][d];
                a_ += fv * al2[d];
                b_ += fv * ar2[d];
            }
            el2[node] = a_;
            er2[node] = b_;
        }
    }
}

// ---------------- agg2: fused edge weights (NO stats fusion) ----------------
__global__ __launch_bounds__(256) void agg2_fused(const float* __restrict__ feat, const float* __restrict__ el,
                                                  const float* __restrict__ er, const int* __restrict__ offs,
                                                  const int* __restrict__ srcs, float* __restrict__ rst,
                                                  int N, int E) {
    const int t = threadIdx.x;
    const int node = blockIdx.x * 8 + (t >> 5);
    const int d = t & 31;
    if (node >= N) return;
    int beg = offs[node], end = offs[node + 1];
    if (beg < 0) beg = 0;
    if (end > E) end = E;
    float ern = er[node];
    float acc = 0.f, sw = 0.f;
#pragma unroll 2
    for (int j = beg; j < end; j++) {
        int s = srcs[j];
        if ((unsigned)s >= (unsigned)N) continue;
        float wv = edgew(el[s] + ern);
        sw += wv;
        acc += wv * feat[(size_t)s * 32 + d];
    }
    rst[(size_t)node * 32 + d] = acc / (sw + 1e-16f);
}

// ---------------- final bn + elu -> f32 out ----------------
__global__ __launch_bounds__(256) void bn_apply2(const float* __restrict__ rst, const float* __restrict__ stats,
                                                 const float* __restrict__ g, const float* __restrict__ b,
                                                 float* __restrict__ out, int total, float invN) {
    int idx = blockIdx.x * 256 + threadIdx.x;
    if (idx >= total) return;
    int c = idx & 31;
    float mu = stats[c] * invN;
    float var = fmaxf(stats[32 + c] * invN - mu * mu, 0.f);
    float y = g[c] * (rst[idx] - mu) * rsqrtf(var + 1e-5f) + b[c];
    y = (y > 0.f) ? y : expm1f(y);
    out[idx] = y;
}

extern "C" void kernel_launch(void* const* d_in, const int* in_sizes, int n_in, void* d_out, int out_size, void* d_ws,
                              size_t ws_size, hipStream_t stream) {
    const int N = out_size / ODIM;
    const int E = in_sizes[2];

    const int* src = (const int*)d_in[2];
    const int* dst = (const int*)d_in[3];
    const float* in_h = (const float*)d_in[0];
    const float* W_emb = (const float*)d_in[4];  const float* b_emb = (const float*)d_in[5];
    const float* fc1 = (const float*)d_in[18];   const float* al1 = (const float*)d_in[19];
    const float* ar1 = (const float*)d_in[20];
    const float* g1 = (const float*)d_in[21];    const float* b1 = (const float*)d_in[22];
    const float* fc2 = (const float*)d_in[23];   const float* al2 = (const float*)d_in[24];
    const float* ar2 = (const float*)d_in[25];
    const float* g2 = (const float*)d_in[26];    const float* b2 = (const float*)d_in[27];
    float* out = (float*)d_out;

    // ---- ws layout (~26 MB) ----
    char* base = (char*)d_ws;
    size_t off = 0;
    auto alloc = [&](size_t bytes) { void* p = base + off; off += (bytes + 63) & ~63ull; return p; };
    char* zb   = (char*)alloc((size_t)N * 4 + 512 * 4 + 64 * 4);
    int* deg   = (int*)zb;
    float* stats  = (float*)(zb + (size_t)N * 4);
    float* stats2 = stats + 512;
    int* offs  = (int*)alloc((size_t)(N + 1) * 4);
    int* cursor = (int*)alloc((size_t)N * 4);
    int* srcs  = (int*)alloc((size_t)E * 4);
    u16* Ah    = (u16*)alloc((size_t)N * 128 * 2);
    u16* Bemb  = (u16*)alloc((size_t)128 * 256 * 2);
    u16* Bfc1  = (u16*)alloc((size_t)256 * 256 * 2);
    u16* Bfc2  = (u16*)alloc((size_t)256 * 32 * 2);
    u16* hh    = (u16*)alloc((size_t)N * HDIM * 2);
    u16* feat1 = (u16*)alloc((size_t)N * HDIM * 2);
    u16* el1   = (u16*)alloc((size_t)N * 8 * 2);
    u16* er1   = (u16*)alloc((size_t)N * 8 * 2);
    u16* rst   = (u16*)alloc((size_t)N * HDIM * 2);
    float* feat2 = (float*)alloc((size_t)N * 32 * 4);
    float* el2 = (float*)alloc((size_t)N * 4);
    float* er2 = (float*)alloc((size_t)N * 4);
    float* rst2 = (float*)alloc((size_t)N * 32 * 4);

    const int NB16 = (N + 15) / 16;
    const int NB64 = (N + 63) / 64;

    hipMemsetAsync(zb, 0, (size_t)N * 4 + 512 * 4 + 64 * 4, stream);
    prep_kernel<<<dim3((N * 128 / 4 + 255) / 256, 5), 256, 0, stream>>>(in_h, W_emb, fc1, fc2, dst, deg,
                                                                        Ah, Bemb, Bfc1, Bfc2, N * 128 / 4, E, N);
    scan_kernel<<<1, 256, 0, stream>>>(deg, offs, cursor, N);
    fill_kernel<<<(E + 255) / 256, 256, 0, stream>>>(src, dst, cursor, srcs, E, N);
    fused_emb_fc1<<<NB16, 256, 0, stream>>>(Ah, Bemb, b_emb, Bfc1, al1, ar1, hh, feat1, el1, er1, N);
    agg1_fused<<<(N + 3) / 4, 256, 0, stream>>>(feat1, el1, er1, offs, srcs, rst, N, E);
    bn_stats256<<<(N + 39) / 40, 256, 0, stream>>>(rst, stats, N, 40);
    gemm_fc2_fused<<<NB64, 256, 0, stream>>>(rst, hh, stats, g1, b1, Bfc2, al2, ar2, feat2, el2, er2, N, 1.f / N);
    agg2_fused<<<(N + 7) / 8, 256, 0, stream>>>(feat2, el2, er2, offs, srcs, rst2, N, E);
    bn_stats32<<<(N + 63) / 64, 256, 0, stream>>>(rst2, stats2, N, 64);
    bn_apply2<<<(N * ODIM + 255) / 256, 256, 0, stream>>>(rst2, stats2, g2, b2, out, N * ODIM, 1.f / N);
}

// Round 3
// 251.992 us; speedup vs baseline: 1.1352x; 1.0296x over previous
//
#include <hip/hip_runtime.h>
#include <hip/hip_bf16.h>
#include <math.h>

// GATNet: hh = h@W_emb+b_emb -> GAT(8 heads,32,residual) -> GAT(1 head,32) -> out f32.
// Edge-feature branch of the reference is dead code (del e_feat) -> skipped.
// R14: (a) gemm_fc2_fused restructured 64-row -> 16-row tiles (625 blocks) with
//     (ct x K-half) wave split + LDS partial reduction: same latency fix that won R13
//     for emb/fc1 (fc2 was still 157 blocks = 1 wave/SIMD, zero latency hiding).
// (b) CSR fill re-merged into fused_emb_fc1 tail blocks (R12 pattern): -1 dispatch,
//     fill atomics overlap GEMM compute. Attribution question it was split for is
//     resolved (R13: GEMM was the 43us, not fill).
// agg1/agg2/bn_stats/prep/scan kept bit-identical (verified).

#define HDIM 256
#define NHEADS 8
#define ODIM 32

typedef unsigned short u16;
typedef __attribute__((ext_vector_type(8))) short short8;
typedef __attribute__((ext_vector_type(4))) float f32x4;

__device__ __forceinline__ float bf2f(u16 u) { return __uint_as_float(((unsigned)u) << 16); }
__device__ __forceinline__ u16 f2bf(float f) {
    unsigned x = __float_as_uint(f);
    return (u16)((x + 0x7FFFu + ((x >> 16) & 1u)) >> 16);  // RNE
}

// ---------------- prep: batched cvt + B swizzles + deg ----------------
__global__ __launch_bounds__(256) void prep_kernel(const float* __restrict__ in_h, const float* __restrict__ W_emb,
                                                   const float* __restrict__ fc1, const float* __restrict__ fc2,
                                                   const int* __restrict__ dstv, int* __restrict__ deg,
                                                   u16* __restrict__ Ah, u16* __restrict__ Bemb,
                                                   u16* __restrict__ Bfc1, u16* __restrict__ Bfc2,
                                                   int n4, int E, int N) {
    int job = blockIdx.y;
    int idx = blockIdx.x * 256 + threadIdx.x;
    if (job == 0) {
        if (idx >= n4) return;
        float4 v = ((const float4*)in_h)[idx];
        ushort4 o = {f2bf(v.x), f2bf(v.y), f2bf(v.z), f2bf(v.w)};
        ((ushort4*)Ah)[idx] = o;
        return;
    }
    if (job == 4) {  // degree count (independent of cvt jobs; deg pre-zeroed by memset)
        if (idx < E) {
            unsigned d = (unsigned)dstv[idx];
            if (d < (unsigned)N) atomicAdd(&deg[d], 1);
        }
        return;
    }
    const float* B;
    u16* O;
    int K, NC;
    if (job == 1) { B = W_emb; O = Bemb; K = 128; NC = 256; }
    else if (job == 2) { B = fc1; O = Bfc1; K = 256; NC = 256; }
    else { B = fc2; O = Bfc2; K = 256; NC = 32; }
    int KB = K / 32;
    int TOT = (NC / 16) * KB * 64;
    if (idx >= TOT) return;
    int lane = idx & 63;
    int kb = (idx >> 6) % KB;
    int ct = (idx >> 6) / KB;
    int n = ct * 16 + (lane & 15);
    int k0 = kb * 32 + (lane >> 4) * 8;
    u16* dst = O + (size_t)idx * 8;
#pragma unroll
    for (int j = 0; j < 8; j++) dst[j] = f2bf(B[(size_t)(k0 + j) * NC + n]);
}

// ---------------- CSR scan (wave-parallel) ----------------
__global__ __launch_bounds__(256) void scan_kernel(const int* __restrict__ deg, int* __restrict__ offs,
                                                   int* __restrict__ cursor, int n) {
    __shared__ int wsum[4];
    int t = threadIdx.x;
    int chunk = (n + 255) / 256;
    int lo = t * chunk, hi = lo + chunk;
    if (hi > n) hi = n;
    if (lo > n) lo = n;
    int s = 0;
    for (int i = lo; i < hi; i++) s += deg[i];
    // inclusive wave scan of s
    int v = s;
#pragma unroll
    for (int d = 1; d < 64; d <<= 1) {
        int nb = __shfl_up(v, d, 64);
        if ((t & 63) >= d) v += nb;
    }
    if ((t & 63) == 63) wsum[t >> 6] = v;
    __syncthreads();
    int woff = 0;
#pragma unroll
    for (int w = 0; w < 4; w++)
        if (w < (t >> 6)) woff += wsum[w];
    int run = woff + v - s;  // exclusive prefix for this thread's chunk
    for (int i = lo; i < hi; i++) {
        offs[i] = run;
        cursor[i] = run;
        run += deg[i];
    }
    if (t == 255) offs[n] = run;  // thread 255's chunk is clamped at n -> run == total
}

// ---------------- fused: emb GEMM -> 8KB LDS -> fc1 GEMM + elr1 (16-row tiles); fill tail ----------------
// GEMM blocks (< NB): 16 output rows, 4 waves each own 4 of the 16 column-tiles (ct).
// Tail blocks (>= NB): CSR fill (atomic cursor scatter), overlapped with GEMM compute.
__global__ __launch_bounds__(256) void fused_emb_fc1(const u16* __restrict__ Ah, const u16* __restrict__ Bemb,
                                                     const float* __restrict__ bemb, const u16* __restrict__ Bfc1,
                                                     const float* __restrict__ al, const float* __restrict__ ar,
                                                     u16* __restrict__ hh, u16* __restrict__ feat1,
                                                     u16* __restrict__ el, u16* __restrict__ er,
                                                     const int* __restrict__ src, const int* __restrict__ dstv,
                                                     int* __restrict__ cursor, int* __restrict__ srcs,
                                                     int M, int NB, int E, int N) {
    if ((int)blockIdx.x >= NB) {  // ---- CSR fill tail (block-uniform branch; barriers below stay uniform) ----
        int i = ((int)blockIdx.x - NB) * 256 + (int)threadIdx.x;
        if (i < E) {
            unsigned d = (unsigned)dstv[i];
            if (d < (unsigned)N) {
                int p = atomicAdd(&cursor[d], 1);
                if ((unsigned)p < (unsigned)E) srcs[p] = src[i];
            }
        }
        return;
    }
    __shared__ u16 tile[16 * 256];  // 8 KB, reused: swizzled hh tile, then plain feat1 tile
    const int t = threadIdx.x;
    const int lane = t & 63, w = t >> 6;
    const int rb = (int)blockIdx.x * 16;
    const int m = lane & 15, q = lane >> 4;
    const int arow = rb + m;

    // ---- stage 1: emb GEMM (K=128), this wave's ct = w*4 .. w*4+3 ----
    short8 a0[4];
#pragma unroll
    for (int kb = 0; kb < 4; kb++) {
        if (arow < M) a0[kb] = *(const short8*)(Ah + (size_t)arow * 128 + kb * 32 + q * 8);
        else a0[kb] = (short8){0, 0, 0, 0, 0, 0, 0, 0};
    }
    const short8* B8 = (const short8*)Bemb;
#pragma unroll
    for (int ct2 = 0; ct2 < 4; ct2++) {
        const int ct = w * 4 + ct2;
        f32x4 acc = {0.f, 0.f, 0.f, 0.f};
#pragma unroll
        for (int kb = 0; kb < 4; kb++)
            acc = __builtin_amdgcn_mfma_f32_16x16x32_bf16(a0[kb], B8[(ct * 4 + kb) * 64 + lane], acc, 0, 0, 0);
        float bv = bemb[ct * 16 + m];
#pragma unroll
        for (int r = 0; r < 4; r++) {
            int rl = q * 4 + r;
            int ro = rb + rl;
            u16 hv = 0;
            if (ro < M) {
                hv = f2bf(acc[r] + bv);
                hh[(size_t)ro * 256 + ct * 16 + m] = hv;
            }
            int byte = rl * 512 + (ct * 16 + m) * 2;
            tile[(byte ^ ((rl & 7) << 4)) >> 1] = hv;  // XOR-swizzle: b128 reads below are ~2-way (free)
        }
    }
    __syncthreads();

    // ---- stage 2: fc1 A-fragments straight from LDS (no global hh re-read) ----
    short8 af[8];
    {
        int rl = m;
#pragma unroll
        for (int kb = 0; kb < 8; kb++) {
            int byte = rl * 512 + kb * 64 + q * 16;
            af[kb] = *(const short8*)(tile + ((byte ^ ((rl & 7) << 4)) >> 1));
        }
    }
    __syncthreads();  // all af reads drained before tile is overwritten as feat1 tile

    const short8* Bf = (const short8*)Bfc1;
#pragma unroll
    for (int ct2 = 0; ct2 < 4; ct2++) {
        const int ct = w * 4 + ct2;
        f32x4 acc = {0.f, 0.f, 0.f, 0.f};
#pragma unroll
        for (int kb = 0; kb < 8; kb++)
            acc = __builtin_amdgcn_mfma_f32_16x16x32_bf16(af[kb], Bf[(ct * 8 + kb) * 64 + lane], acc, 0, 0, 0);
#pragma unroll
        for (int r = 0; r < 4; r++) {
            int rl = q * 4 + r;
            int ro = rb + rl;
            u16 v = 0;
            if (ro < M) {
                v = f2bf(acc[r]);
                feat1[(size_t)ro * 256 + ct * 16 + m] = v;
            }
            tile[rl * 256 + ct * 16 + m] = v;  // plain layout for elr epilogue
        }
    }
    __syncthreads();

    // ---- stage 3: el/er epilogue from feat1 tile (16 nodes x 8 heads = 128 tasks) ----
    if (t < 128) {
        int nl = t >> 3, h2 = t & 7;
        int node = rb + nl;
        if (node < M) {
            float a_ = 0.f, b_ = 0.f;
#pragma unroll
            for (int d = 0; d < 32; d++) {
                float fv = bf2f(tile[nl * 256 + h2 * 32 + d]);
                a_ += fv * al[h2 * 32 + d];
                b_ += fv * ar[h2 * 32 + d];
            }
            el[node * 8 + h2] = f2bf(a_);
            er[node * 8 + h2] = f2bf(b_);
        }
    }
}

// exp(leaky_relu(l)); logits O(0.1), max-subtraction unnecessary (identical ratios)
__device__ __forceinline__ float edgew(float l) {
    l = (l > 0.f) ? l : 0.2f * l;
    l = fminf(fmaxf(l, -30.f), 30.f);
    return __expf(l);
}

// ---------------- agg1: fused edge weights (NO stats fusion) ----------------
__global__ __launch_bounds__(256) void agg1_fused(const u16* __restrict__ feat, const u16* __restrict__ el,
                                                  const u16* __restrict__ er, const int* __restrict__ offs,
                                                  const int* __restrict__ srcs, u16* __restrict__ rst, int N, int E) {
    const int node = blockIdx.x * 4 + (threadIdx.x >> 6);
    const int lane = threadIdx.x & 63;
    if (node >= N) return;
    const int h = lane >> 3;
    int beg = offs[node], end = offs[node + 1];
    if (beg < 0) beg = 0;
    if (end > E) end = E;
    float ern = bf2f(er[node * 8 + h]);
    float ax = 0.f, ay = 0.f, az = 0.f, aw = 0.f, sw = 0.f;
    int j = beg;
    int end4 = beg + ((end - beg) & ~3);
    for (; j < end4; j += 4) {  // 4-deep software pipeline
        int s0 = srcs[j], s1 = srcs[j + 1], s2 = srcs[j + 2], s3 = srcs[j + 3];
        unsigned c0 = (unsigned)s0 < (unsigned)N, c1 = (unsigned)s1 < (unsigned)N;
        unsigned c2 = (unsigned)s2 < (unsigned)N, c3 = (unsigned)s3 < (unsigned)N;
        s0 = c0 ? s0 : 0; s1 = c1 ? s1 : 0; s2 = c2 ? s2 : 0; s3 = c3 ? s3 : 0;
        u16 e0 = el[s0 * 8 + h], e1 = el[s1 * 8 + h], e2 = el[s2 * 8 + h], e3 = el[s3 * 8 + h];
        ushort4 f0 = *(const ushort4*)(feat + (size_t)s0 * 256 + lane * 4);
        ushort4 f1 = *(const ushort4*)(feat + (size_t)s1 * 256 + lane * 4);
        ushort4 f2 = *(const ushort4*)(feat + (size_t)s2 * 256 + lane * 4);
        ushort4 f3 = *(const ushort4*)(feat + (size_t)s3 * 256 + lane * 4);
        float w0 = c0 ? edgew(bf2f(e0) + ern) : 0.f;
        float w1 = c1 ? edgew(bf2f(e1) + ern) : 0.f;
        float w2 = c2 ? edgew(bf2f(e2) + ern) : 0.f;
        float w3 = c3 ? edgew(bf2f(e3) + ern) : 0.f;
        sw += w0 + w1 + w2 + w3;
        ax += w0 * bf2f(f0.x) + w1 * bf2f(f1.x) + w2 * bf2f(f2.x) + w3 * bf2f(f3.x);
        ay += w0 * bf2f(f0.y) + w1 * bf2f(f1.y) + w2 * bf2f(f2.y) + w3 * bf2f(f3.y);
        az += w0 * bf2f(f0.z) + w1 * bf2f(f1.z) + w2 * bf2f(f2.z) + w3 * bf2f(f3.z);
        aw += w0 * bf2f(f0.w) + w1 * bf2f(f1.w) + w2 * bf2f(f2.w) + w3 * bf2f(f3.w);
    }
    for (; j < end; j++) {
        int s = srcs[j];
        if ((unsigned)s >= (unsigned)N) continue;
        float wv = edgew(bf2f(el[s * 8 + h]) + ern);
        ushort4 f4 = *(const ushort4*)(feat + (size_t)s * 256 + lane * 4);
        sw += wv;
        ax += wv * bf2f(f4.x);
        ay += wv * bf2f(f4.y);
        az += wv * bf2f(f4.z);
        aw += wv * bf2f(f4.w);
    }
    float inv = 1.f / (sw + 1e-16f);
    ushort4 o;
    o.x = f2bf(ax * inv); o.y = f2bf(ay * inv); o.z = f2bf(az * inv); o.w = f2bf(aw * inv);
    *(ushort4*)(rst + (size_t)node * 256 + lane * 4) = o;
}

// ---------------- bn stats, separate low-contention kernels ----------------
__global__ __launch_bounds__(256) void bn_stats256(const u16* __restrict__ X, float* __restrict__ stats,
                                                   int rows, int RPB) {
    int t = threadIdx.x;
    int rbeg = blockIdx.x * RPB;
    int rend = rbeg + RPB;
    if (rend > rows) rend = rows;
    float s = 0.f, s2 = 0.f;
    for (int r = rbeg; r < rend; r++) {
        float x = bf2f(X[(long)r * 256 + t]);
        s += x;
        s2 += x * x;
    }
    atomicAdd(&stats[t], s);
    atomicAdd(&stats[256 + t], s2);
}

__global__ __launch_bounds__(256) void bn_stats32(const float* __restrict__ X, float* __restrict__ stats,
                                                  int rows, int RPB) {
    __shared__ float ss[256], ss2[256];
    int t = threadIdx.x, c = t & 31, rs = t >> 5;
    int rbeg = blockIdx.x * RPB;
    int rend = rbeg + RPB;
    if (rend > rows) rend = rows;
    float s = 0.f, s2 = 0.f;
    for (int r = rbeg + rs; r < rend; r += 8) {
        float x = X[(long)r * 32 + c];
        s += x;
        s2 += x * x;
    }
    ss[t] = s;
    ss2[t] = s2;
    __syncthreads();
    if (t < 32) {
        for (int j = 32; j < 256; j += 32) { s += ss[t + j]; s2 += ss2[t + j]; }
        atomicAdd(&stats[c], s);
        atomicAdd(&stats[32 + c], s2);
    }
}

// ---------------- fc2 GEMM, 16-row tiles, (ct x K-half) wave split + LDS reduce ----------------
// Block = 16 rows (625 blocks). Wave w: ct = w&1 (of 2 column-tiles), kh = w>>1 (K half).
// Waves 2,3 write f32x4 partials to LDS; waves 0,1 reduce, store feat2 + elr tile.
// bn_apply1(+residual+elu) fused into the A-fragment load (per wave's K-slice).
__global__ __launch_bounds__(256) void gemm_fc2_fused(const u16* __restrict__ rst, const u16* __restrict__ hh,
                                                      const float* __restrict__ stats, const float* __restrict__ g,
                                                      const float* __restrict__ b, const u16* __restrict__ Bsw,
                                                      const float* __restrict__ al2, const float* __restrict__ ar2,
                                                      float* __restrict__ feat2, float* __restrict__ el2,
                                                      float* __restrict__ er2, int M, float invN) {
    __shared__ float sc[256], sh[256];
    __shared__ float red[2][256];   // partial acc from waves 2,3 (per ct: 64 lanes x f32x4)
    __shared__ float tile[16][32];
    const int t = threadIdx.x;
    {
        float mu = stats[t] * invN;
        float var = fmaxf(stats[256 + t] * invN - mu * mu, 0.f);
        float s = g[t] * rsqrtf(var + 1e-5f);
        sc[t] = s;
        sh[t] = b[t] - mu * s;
    }
    __syncthreads();
    const int lane = t & 63, w = t >> 6;
    const int ct = w & 1, kh = w >> 1;
    const int rb = (int)blockIdx.x * 16;
    const int m = lane & 15, q = lane >> 4;
    const int row = rb + m;
    short8 a[4];
#pragma unroll
    for (int j = 0; j < 4; j++) {
        if (row < M) {
            int k0 = (kh * 4 + j) * 32 + q * 8;
            ushort4 r01 = *(const ushort4*)(rst + (size_t)row * 256 + k0);
            ushort4 r23 = *(const ushort4*)(rst + (size_t)row * 256 + k0 + 4);
            ushort4 h01 = *(const ushort4*)(hh + (size_t)row * 256 + k0);
            ushort4 h23 = *(const ushort4*)(hh + (size_t)row * 256 + k0 + 4);
            u16 rv[8] = {r01.x, r01.y, r01.z, r01.w, r23.x, r23.y, r23.z, r23.w};
            u16 hv[8] = {h01.x, h01.y, h01.z, h01.w, h23.x, h23.y, h23.z, h23.w};
            short8 av;
#pragma unroll
            for (int jj = 0; jj < 8; jj++) {
                int c = k0 + jj;
                float y = sc[c] * bf2f(rv[jj]) + sh[c];
                y = (y > 0.f) ? y : expm1f(y);
                av[jj] = (short)f2bf(bf2f(hv[jj]) + y);
            }
            a[j] = av;
        } else a[j] = (short8){0, 0, 0, 0, 0, 0, 0, 0};
    }
    const short8* B8 = (const short8*)Bsw;
    f32x4 acc = {0.f, 0.f, 0.f, 0.f};
#pragma unroll
    for (int j = 0; j < 4; j++)
        acc = __builtin_amdgcn_mfma_f32_16x16x32_bf16(a[j], B8[(ct * 8 + kh * 4 + j) * 64 + lane], acc, 0, 0, 0);
    if (kh == 1) *(f32x4*)&red[ct][lane * 4] = acc;
    __syncthreads();
    if (kh == 0) {
        f32x4 p = *(const f32x4*)&red[ct][lane * 4];
#pragma unroll
        for (int r = 0; r < 4; r++) {
            int rl = q * 4 + r;
            int ro = rb + rl;
            float v = 0.f;
            if (ro < M) {
                v = acc[r] + p[r];
                feat2[(size_t)ro * 32 + ct * 16 + m] = v;
            }
            tile[rl][ct * 16 + m] = v;
        }
    }
    __syncthreads();
    if (t < 16) {
        int node = rb + t;
        if (node < M) {
            float a_ = 0.f, b_ = 0.f;
#pragma unroll
            for (int d = 0; d < 32; d++) {
                float fv = tile[t][d];
                a_ += fv * al2[d];
                b_ += fv * ar2[d];
            }
            el2[node] = a_;
            er2[node] = b_;
        }
    }
}

// ---------------- agg2: fused edge weights (NO stats fusion) ----------------
__global__ __launch_bounds__(256) void agg2_fused(const float* __restrict__ feat, const float* __restrict__ el,
                                                  const float* __restrict__ er, const int* __restrict__ offs,
                                                  const int* __restrict__ srcs, float* __restrict__ rst,
                                                  int N, int E) {
    const int t = threadIdx.x;
    const int node = blockIdx.x * 8 + (t >> 5);
    const int d = t & 31;
    if (node >= N) return;
    int beg = offs[node], end = offs[node + 1];
    if (beg < 0) beg = 0;
    if (end > E) end = E;
    float ern = er[node];
    float acc = 0.f, sw = 0.f;
#pragma unroll 2
    for (int j = beg; j < end; j++) {
        int s = srcs[j];
        if ((unsigned)s >= (unsigned)N) continue;
        float wv = edgew(el[s] + ern);
        sw += wv;
        acc += wv * feat[(size_t)s * 32 + d];
    }
    rst[(size_t)node * 32 + d] = acc / (sw + 1e-16f);
}

// ---------------- final bn + elu -> f32 out ----------------
__global__ __launch_bounds__(256) void bn_apply2(const float* __restrict__ rst, const float* __restrict__ stats,
                                                 const float* __restrict__ g, const float* __restrict__ b,
                                                 float* __restrict__ out, int total, float invN) {
    int idx = blockIdx.x * 256 + threadIdx.x;
    if (idx >= total) return;
    int c = idx & 31;
    float mu = stats[c] * invN;
    float var = fmaxf(stats[32 + c] * invN - mu * mu, 0.f);
    float y = g[c] * (rst[idx] - mu) * rsqrtf(var + 1e-5f) + b[c];
    y = (y > 0.f) ? y : expm1f(y);
    out[idx] = y;
}

extern "C" void kernel_launch(void* const* d_in, const int* in_sizes, int n_in, void* d_out, int out_size, void* d_ws,
                              size_t ws_size, hipStream_t stream) {
    const int N = out_size / ODIM;
    const int E = in_sizes[2];

    const int* src = (const int*)d_in[2];
    const int* dst = (const int*)d_in[3];
    const float* in_h = (const float*)d_in[0];
    const float* W_emb = (const float*)d_in[4];  const float* b_emb = (const float*)d_in[5];
    const float* fc1 = (const float*)d_in[18];   const float* al1 = (const float*)d_in[19];
    const float* ar1 = (const float*)d_in[20];
    const float* g1 = (const float*)d_in[21];    const float* b1 = (const float*)d_in[22];
    const float* fc2 = (const float*)d_in[23];   const float* al2 = (const float*)d_in[24];
    const float* ar2 = (const float*)d_in[25];
    const float* g2 = (const float*)d_in[26];    const float* b2 = (const float*)d_in[27];
    float* out = (float*)d_out;

    // ---- ws layout (~26 MB) ----
    char* base = (char*)d_ws;
    size_t off = 0;
    auto alloc = [&](size_t bytes) { void* p = base + off; off += (bytes + 63) & ~63ull; return p; };
    char* zb   = (char*)alloc((size_t)N * 4 + 512 * 4 + 64 * 4);
    int* deg   = (int*)zb;
    float* stats  = (float*)(zb + (size_t)N * 4);
    float* stats2 = stats + 512;
    int* offs  = (int*)alloc((size_t)(N + 1) * 4);
    int* cursor = (int*)alloc((size_t)N * 4);
    int* srcs  = (int*)alloc((size_t)E * 4);
    u16* Ah    = (u16*)alloc((size_t)N * 128 * 2);
    u16* Bemb  = (u16*)alloc((size_t)128 * 256 * 2);
    u16* Bfc1  = (u16*)alloc((size_t)256 * 256 * 2);
    u16* Bfc2  = (u16*)alloc((size_t)256 * 32 * 2);
    u16* hh    = (u16*)alloc((size_t)N * HDIM * 2);
    u16* feat1 = (u16*)alloc((size_t)N * HDIM * 2);
    u16* el1   = (u16*)alloc((size_t)N * 8 * 2);
    u16* er1   = (u16*)alloc((size_t)N * 8 * 2);
    u16* rst   = (u16*)alloc((size_t)N * HDIM * 2);
    float* feat2 = (float*)alloc((size_t)N * 32 * 4);
    float* el2 = (float*)alloc((size_t)N * 4);
    float* er2 = (float*)alloc((size_t)N * 4);
    float* rst2 = (float*)alloc((size_t)N * 32 * 4);

    const int NB16 = (N + 15) / 16;
    const int NBF = (E + 255) / 256;  // fill tail blocks

    hipMemsetAsync(zb, 0, (size_t)N * 4 + 512 * 4 + 64 * 4, stream);
    prep_kernel<<<dim3((N * 128 / 4 + 255) / 256, 5), 256, 0, stream>>>(in_h, W_emb, fc1, fc2, dst, deg,
                                                                        Ah, Bemb, Bfc1, Bfc2, N * 128 / 4, E, N);
    scan_kernel<<<1, 256, 0, stream>>>(deg, offs, cursor, N);
    fused_emb_fc1<<<NB16 + NBF, 256, 0, stream>>>(Ah, Bemb, b_emb, Bfc1, al1, ar1, hh, feat1, el1, er1,
                                                  src, dst, cursor, srcs, N, NB16, E, N);
    agg1_fused<<<(N + 3) / 4, 256, 0, stream>>>(feat1, el1, er1, offs, srcs, rst, N, E);
    bn_stats256<<<(N + 39) / 40, 256, 0, stream>>>(rst, stats, N, 40);
    gemm_fc2_fused<<<NB16, 256, 0, stream>>>(rst, hh, stats, g1, b1, Bfc2, al2, ar2, feat2, el2, er2, N, 1.f / N);
    agg2_fused<<<(N + 7) / 8, 256, 0, stream>>>(feat2, el2, er2, offs, srcs, rst2, N, E);
    bn_stats32<<<(N + 63) / 64, 256, 0, stream>>>(rst2, stats2, N, 64);
    bn_apply2<<<(N * ODIM + 255) / 256, 256, 0, stream>>>(rst2, stats2, g2, b2, out, N * ODIM, 1.f / N);
}